// Round 6
// baseline (177.129 us; speedup 1.0000x reference)
//
#include <hip/hip_runtime.h>
#include <math.h>

// Problem constants
#define BB 8
#define LL 1024
#define SS 1024
#define CC 128
#define NN 8
#define PP 256

static constexpr float EPS       = 1e-6f;
static constexpr float ONE_M_EPS = 1.0f - 1e-6f;
static constexpr float INV_T     = 1.0f / 0.07f;
static constexpr float NLL_MAX   = 13.815511f;    // -log(1e-6)
static constexpr float NLL_MIN   = 1.0000005e-6f; // -log(1-1e-6)

// Workspace layout (float offsets)
static constexpr size_t DOTSZ      = (size_t)BB * LL * SS;   // 8388608
static constexpr size_t OFF_LSER   = DOTSZ;                  // B*L
static constexpr size_t OFF_S2RAW  = DOTSZ + 8192;           // B*L
static constexpr size_t OFF_LSEC   = DOTSZ + 16384;          // B*S
static constexpr size_t OFF_S1RAW  = DOTSZ + 24576;          // B*S
static constexpr size_t OFF_SHARP2 = DOTSZ + 32768;          // B*L
static constexpr size_t OFF_CP     = DOTSZ + 40960;          // col partials: 8*64*1024*4 = 2097152
static constexpr size_t OFF_ACC    = OFF_CP + 2097152;       // B*6
static constexpr size_t OFF_ACCCL  = OFF_ACC + 48;           // 2
static constexpr size_t OFF_QN     = OFF_ACC + 64;           // 8*128 normalized q_sel
static constexpr size_t OFF_AH     = OFF_ACC + 2048;         // Ahat bf16 (B*L*384 shorts = 1572864 floats)
static constexpr size_t OFF_BH     = OFF_AH + 1572864;       // Bhat bf16

// Output layout (floats): sharp1[8192], cl_pos_save[1024], total, geo_pos, geo_neg, loss_sharp, loss_cl
static constexpr int OUT_CLSAVE = 8192;
static constexpr int OUT_SCAL   = 9216;

typedef __bf16 bf16x8 __attribute__((ext_vector_type(8)));
typedef float  floatx4 __attribute__((ext_vector_type(4)));

__device__ __forceinline__ void gld_lds16(const void* g, void* l) {
    __builtin_amdgcn_global_load_lds(
        (const __attribute__((address_space(1))) void*)g,
        (__attribute__((address_space(3))) void*)l, 16, 0, 0);
}

// Split a float2 into packed bf16-hi pair (RNE) and bf16-lo pair (exact residual, truncated)
__device__ __forceinline__ void split2(float2 x, unsigned& hp, unsigned& lp) {
    unsigned u0 = __builtin_bit_cast(unsigned, x.x);
    unsigned u1 = __builtin_bit_cast(unsigned, x.y);
    unsigned r0 = u0 + 0x7FFFu + ((u0 >> 16) & 1u);
    unsigned r1 = u1 + 0x7FFFu + ((u1 >> 16) & 1u);
    float s0 = x.x - __builtin_bit_cast(float, r0 & 0xFFFF0000u);
    float s1 = x.y - __builtin_bit_cast(float, r1 & 0xFFFF0000u);
    hp = __builtin_amdgcn_perm(r1, r0, 0x07060302u);
    lp = __builtin_amdgcn_perm(__builtin_bit_cast(unsigned, s1),
                               __builtin_bit_cast(unsigned, s0), 0x07060302u);
}

// ---------------- Prep: zero accumulators, normalize q_sel, write cl_pos_save ----------------
__global__ __launch_bounds__(512) void prep(const float* __restrict__ q_cl,
                                            const float* __restrict__ cl_pos,
                                            const int* __restrict__ idx,
                                            float* __restrict__ out, float* __restrict__ ws) {
    int tid = threadIdx.x;
    if (tid < 50) ws[OFF_ACC + tid] = 0.0f;
    int n = tid >> 6, lane = tid & 63;
    int in = idx[n];
    const float* q = q_cl + ((size_t)(n * PP + in)) * CC;
    float2 qv = *(const float2*)(q + 2 * lane);
    float ss = qv.x * qv.x + qv.y * qv.y;
    for (int o = 32; o; o >>= 1) ss += __shfl_xor(ss, o);
    float inv = 1.0f / fmaxf(sqrtf(ss), 1e-12f);
    *(float2*)(ws + OFF_QN + n * 128 + 2 * lane) = make_float2(qv.x * inv, qv.y * inv);
    const float* cp = cl_pos + ((size_t)(n * PP + in)) * CC;
    float2 cv = *(const float2*)(cp + 2 * lane);
    *(float2*)(out + OUT_CLSAVE + n * 128 + 2 * lane) = cv;
}

// ---------------- Convert: fp32 -> split-bf16 K=384 operands ----------------
// Ahat row = [Ah(128) | Ah(128) | Al(128)], Bhat row = [Bh(128) | Bl(128) | Bh(128)]
// so Ahat . Bhat over k=0..383 = hi.hi + hi.lo + lo.hi (fp32-grade).
__global__ __launch_bounds__(256) void convert(const float* __restrict__ q_geo,
                                               const float* __restrict__ geo_pos,
                                               float* __restrict__ ws) {
    int r = blockIdx.x * 4 + (threadIdx.x >> 6);   // 0..16383
    int lane = threadIdx.x & 63;
    bool isB = r >= 8192;
    int rr = isB ? r - 8192 : r;
    const float* src = (isB ? geo_pos : q_geo) + (size_t)rr * CC + 2 * lane;
    short* dst = (short*)(ws + (isB ? OFF_BH : OFF_AH)) + (size_t)rr * 384 + 2 * lane;
    float2 v = *(const float2*)src;
    unsigned hp, lp;
    split2(v, hp, lp);
    *(unsigned*)(dst + 0)   = hp;
    *(unsigned*)(dst + 128) = isB ? lp : hp;
    *(unsigned*)(dst + 256) = isB ? hp : lp;
}

// ---------------- GEMM (m97 pattern): dot = Ahat . Bhat^T, K=384 bf16 ----------------
__global__ __launch_bounds__(256) void gemm_dot(const float* __restrict__ wsc,
                                                float* __restrict__ dot) {
    int b  = blockIdx.z;
    int l0 = blockIdx.y * 128;
    int s0 = blockIdx.x * 128;
    __shared__ short As[128 * 32];   // 8 KB
    __shared__ short Bs[128 * 32];   // 8 KB

    int tid  = threadIdx.x;
    int lane = tid & 63;
    int w    = tid >> 6;
    int wr   = (w >> 1) * 64;
    int wc   = (w & 1) * 64;
    int fl   = lane & 15;
    int quad = lane >> 4;

    const short* AH = (const short*)(wsc + OFF_AH) + ((size_t)(b * 1024 + l0)) * 384;
    const short* BH = (const short*)(wsc + OFF_BH) + ((size_t)(b * 1024 + s0)) * 384;

    floatx4 acc[4][4];
#pragma unroll
    for (int i = 0; i < 4; i++)
#pragma unroll
        for (int j = 0; j < 4; j++) acc[i][j] = (floatx4){0.f, 0.f, 0.f, 0.f};

    for (int kk = 0; kk < 12; kk++) {
        int k0 = kk * 32;
        // Stage 16 KB via global_load_lds width=16 (wave-uniform base + lane*16)
#pragma unroll
        for (int rep = 0; rep < 2; rep++) {
            int c   = tid + rep * 256;          // 0..511 16-B chunks
            int row = c >> 2;
            int ko  = (c & 3) * 8;
            gld_lds16(AH + (size_t)row * 384 + k0 + ko, &As[c * 8]);
            gld_lds16(BH + (size_t)row * 384 + k0 + ko, &Bs[c * 8]);
        }
        __syncthreads();   // compiler drains vmcnt before barrier

        bf16x8 af[4], bf[4];
#pragma unroll
        for (int mt = 0; mt < 4; mt++)
            af[mt] = *reinterpret_cast<const bf16x8*>(&As[(wr + mt * 16 + fl) * 32 + quad * 8]);
#pragma unroll
        for (int nt = 0; nt < 4; nt++)
            bf[nt] = *reinterpret_cast<const bf16x8*>(&Bs[(wc + nt * 16 + fl) * 32 + quad * 8]);
#pragma unroll
        for (int nt = 0; nt < 4; nt++)
#pragma unroll
            for (int mt = 0; mt < 4; mt++)
                acc[mt][nt] = __builtin_amdgcn_mfma_f32_16x16x32_bf16(af[mt], bf[nt], acc[mt][nt], 0, 0, 0);
        __syncthreads();   // protect LDS for next stage
    }

    // C/D layout: col=lane&15, row=quad*4+reg
    float* D = dot + ((size_t)b * LL + l0) * SS + s0;
#pragma unroll
    for (int mt = 0; mt < 4; mt++)
#pragma unroll
        for (int nt = 0; nt < 4; nt++) {
            int col = wc + nt * 16 + fl;
#pragma unroll
            for (int r = 0; r < 4; r++) {
                int row = wr + mt * 16 + quad * 4 + r;
                D[(size_t)row * SS + col] = acc[mt][nt][r];
            }
        }
}

// ---------------- Single-pass stats: rows final, columns 16-deep partials ----------------
// Block = (b, 16-row chunk). 256 threads x 4 cols = full 1024-col rows in-block.
__global__ __launch_bounds__(256) void stats(const float* __restrict__ dot, float* __restrict__ ws) {
    int b  = blockIdx.x >> 6;
    int lc = blockIdx.x & 63;
    int tid = threadIdx.x;
    int col0 = tid * 4;
    float res[16], rmx[16], rsm[16], rsq[16];
    float ces[4] = {0, 0, 0, 0}, csm[4] = {0, 0, 0, 0}, csq[4] = {0, 0, 0, 0};
    float cmx[4] = {-1e30f, -1e30f, -1e30f, -1e30f};
#pragma unroll
    for (int r = 0; r < 16; r++) {
        int row = lc * 16 + r;
        float4 d4 = *(const float4*)(dot + ((size_t)(b * 1024 + row)) * 1024 + col0);
        float vals[4] = {d4.x, d4.y, d4.z, d4.w};
        float es = 0.f, mx = -1e30f, sm = 0.f, sq = 0.f;
#pragma unroll
        for (int j = 0; j < 4; j++) {
            float d  = vals[j];
            float e  = __expf(d * INV_T);
            float s2 = fmaf(0.5f, d, 0.5f);
            es += e; mx = fmaxf(mx, s2); sm += s2; sq += s2 * s2;
            ces[j] += e; cmx[j] = fmaxf(cmx[j], s2); csm[j] += s2; csq[j] += s2 * s2;
        }
        res[r] = es; rmx[r] = mx; rsm[r] = sm; rsq[r] = sq;
    }
    // column partials (16-deep) -> OFF_CP
#pragma unroll
    for (int j = 0; j < 4; j++) {
        *(float4*)(ws + OFF_CP + (((size_t)(b * 64 + lc)) * 1024 + col0 + j) * 4) =
            make_float4(ces[j], cmx[j], csm[j], csq[j]);
    }
    // row reduction: wave shuffles then cross-wave via LDS
    __shared__ float sred[16][4][4];   // [row][wave][stat]
    int lane = tid & 63, wid = tid >> 6;
#pragma unroll
    for (int r = 0; r < 16; r++) {
        float es = res[r], mx = rmx[r], sm = rsm[r], sq = rsq[r];
        for (int o = 32; o; o >>= 1) {
            es += __shfl_xor(es, o);
            mx = fmaxf(mx, __shfl_xor(mx, o));
            sm += __shfl_xor(sm, o);
            sq += __shfl_xor(sq, o);
        }
        if (!lane) { sred[r][wid][0] = es; sred[r][wid][1] = mx; sred[r][wid][2] = sm; sred[r][wid][3] = sq; }
    }
    __syncthreads();
    if (tid < 16) {
        float es = 0.f, mx = -1e30f, sm = 0.f, sq = 0.f;
#pragma unroll
        for (int w2 = 0; w2 < 4; w2++) {
            es += sred[tid][w2][0];
            mx = fmaxf(mx, sred[tid][w2][1]);
            sm += sred[tid][w2][2];
            sq += sred[tid][w2][3];
        }
        int l = lc * 16 + tid;
        ws[OFF_LSER + (size_t)b * 1024 + l] = __logf(es);
        float mean = sm * (1.0f / 1024.0f);
        float var  = (sq - sm * sm * (1.0f / 1024.0f)) * (1.0f / 1023.0f);
        ws[OFF_S2RAW + (size_t)b * 1024 + l] = (mx - mean) / sqrtf(fmaxf(var, 1e-30f));
    }
}

// ---------------- Column combine: 64 partials -> LSEC/S1RAW ----------------
__global__ __launch_bounds__(256) void ccomb(float* __restrict__ ws) {
    int g = blockIdx.x * 256 + threadIdx.x;  // 0..8191
    int b = g >> 10, s = g & 1023;
    float es = 0.f, mx = -1e30f, sm = 0.f, sq = 0.f;
    for (int t = 0; t < 64; t++) {
        float4 v = *(const float4*)(ws + OFF_CP + (((size_t)(b * 64 + t)) * 1024 + s) * 4);
        es += v.x; mx = fmaxf(mx, v.y); sm += v.z; sq += v.w;
    }
    ws[OFF_LSEC + g] = __logf(es);
    float mean = sm * (1.0f / 1024.0f);
    float var  = (sq - sm * sm * (1.0f / 1024.0f)) * (1.0f / 1023.0f);
    ws[OFF_S1RAW + g] = (mx - mean) / sqrtf(fmaxf(var, 1e-30f));
}

// ---------------- 16 softmaxes of length 1024: 0..7 -> sharp1 (d_out), 8..15 -> sharp2 (ws) ----
__global__ __launch_bounds__(256) void softmax16(float* __restrict__ ws, float* __restrict__ out) {
    int q = blockIdx.x;
    int b = q & 7;
    const float* src = ws + ((q < 8) ? OFF_S1RAW : OFF_S2RAW) + (size_t)b * 1024;
    float* dst = (q < 8) ? (out + (size_t)b * 1024) : (ws + OFF_SHARP2 + (size_t)b * 1024);
    float4 v = ((const float4*)src)[threadIdx.x];
    int lane = threadIdx.x & 63, wid = threadIdx.x >> 6;
    __shared__ float sb[4];
    __shared__ float red;
    float mx = fmaxf(fmaxf(v.x, v.y), fmaxf(v.z, v.w));
    for (int o = 32; o; o >>= 1) mx = fmaxf(mx, __shfl_xor(mx, o));
    if (!lane) sb[wid] = mx;
    __syncthreads();
    if (threadIdx.x == 0) red = fmaxf(fmaxf(sb[0], sb[1]), fmaxf(sb[2], sb[3]));
    __syncthreads();
    mx = red;
    float e0 = __expf(v.x - mx), e1 = __expf(v.y - mx), e2 = __expf(v.z - mx), e3 = __expf(v.w - mx);
    float sm = e0 + e1 + e2 + e3;
    for (int o = 32; o; o >>= 1) sm += __shfl_xor(sm, o);
    __syncthreads();
    if (!lane) sb[wid] = sm;
    __syncthreads();
    if (threadIdx.x == 0) red = sb[0] + sb[1] + sb[2] + sb[3];
    __syncthreads();
    float inv = 1.0f / red;
    ((float4*)dst)[threadIdx.x] = make_float4(e0 * inv, e1 * inv, e2 * inv, e3 * inv);
}

// ---------------- Main elementwise loss pass (branchless) ----------------
__device__ __forceinline__ void proc_elem(float d, int lab, float lcj, float sh1j,
                                          float lr, float s2v,
                                          float& posg, float& negg, float& l1, float& l2,
                                          float& negs, float& pcf) {
    float t = lr + lcj - d * (2.0f * INV_T);   // -log(conf_geo)
    float isPos = (lab == 1) ? 1.0f : 0.0f;
    float isNeg = 1.0f - isPos;
    float tp   = fminf(fmaxf(t, NLL_MIN), NLL_MAX);
    float simc = fminf(fmaxf(fmaf(0.5f, d, 0.5f), EPS), ONE_M_EPS);
    float om   = fminf(fmaxf(fmaf(-0.5f, d, 0.5f), EPS), ONE_M_EPS);
    float nll2 = -__logf(simc);
    float cf   = fminf(fmaxf(__expf(-t), EPS), ONE_M_EPS);
    float nllg = -__logf(1.0f - cf);
    float nlls = -__logf(om);
    posg += isPos * tp;
    l1   += isPos * nll2 * sh1j;
    l2   += isPos * nll2 * s2v;
    pcf  += isPos;
    negg += isNeg * nllg;
    negs += isNeg * nlls;
}

__global__ __launch_bounds__(256) void main_loss(const float* __restrict__ dot,
                                                 const int* __restrict__ label,
                                                 const float* __restrict__ sharp1,
                                                 float* __restrict__ ws) {
    int b = blockIdx.y;
    int l0 = blockIdx.x * 4;
    int s = threadIdx.x * 4;
    float4 lc4 = *(const float4*)(ws + OFF_LSEC + (size_t)b * 1024 + s);
    float4 sh1 = *(const float4*)(sharp1 + (size_t)b * 1024 + s);
    const float* lser = ws + OFF_LSER + (size_t)b * 1024;
    const float* sh2  = ws + OFF_SHARP2 + (size_t)b * 1024;
    float posg = 0, negg = 0, l1 = 0, l2 = 0, negs = 0, pcf = 0;
#pragma unroll
    for (int r = 0; r < 4; r++) {
        int l = l0 + r;
        float lr  = lser[l];
        float s2v = sh2[l];
        size_t base = ((size_t)(b * 1024 + l)) * 1024 + s;
        float4 d4 = *(const float4*)(dot + base);
        int4  lb  = *(const int4*)(label + base);
        proc_elem(d4.x, lb.x, lc4.x, sh1.x, lr, s2v, posg, negg, l1, l2, negs, pcf);
        proc_elem(d4.y, lb.y, lc4.y, sh1.y, lr, s2v, posg, negg, l1, l2, negs, pcf);
        proc_elem(d4.z, lb.z, lc4.z, sh1.z, lr, s2v, posg, negg, l1, l2, negs, pcf);
        proc_elem(d4.w, lb.w, lc4.w, sh1.w, lr, s2v, posg, negg, l1, l2, negs, pcf);
    }
    float vals[6] = {posg, negg, l1, l2, negs, pcf};
    __shared__ float sb[6][4];
    int lane = threadIdx.x & 63, wid = threadIdx.x >> 6;
#pragma unroll
    for (int k = 0; k < 6; k++) {
        float v = vals[k];
        for (int o = 32; o; o >>= 1) v += __shfl_xor(v, o);
        if (!lane) sb[k][wid] = v;
    }
    __syncthreads();
    if (threadIdx.x < 6) {
        float r = sb[threadIdx.x][0] + sb[threadIdx.x][1] + sb[threadIdx.x][2] + sb[threadIdx.x][3];
        atomicAdd(ws + OFF_ACC + (size_t)b * 6 + threadIdx.x, r);
    }
}

// ---------------- Contrast loss: one wave per all_k row j ----------------
__global__ __launch_bounds__(256) void contrast(const float* __restrict__ cl_pos,
                                                const int* __restrict__ idx,
                                                float* __restrict__ ws) {
    int j = blockIdx.x * 4 + (threadIdx.x >> 6);
    int lane = threadIdx.x & 63;
    int m, p;
    if (j < NN) {
        m = j; p = idx[j];
    } else {
        int jj = j - NN;
        m = jj / (PP - 1);
        p = 1 + (jj - m * (PP - 1));
        if (p == idx[m]) p = 0;
    }
    const float* k = cl_pos + ((size_t)(m * PP + p)) * CC;
    float2 kv = *(const float2*)(k + 2 * lane);
    float ksq = kv.x * kv.x + kv.y * kv.y;
    for (int o = 32; o; o >>= 1) ksq += __shfl_xor(ksq, o);
    float invkn = 1.0f / fmaxf(sqrtf(ksq), 1e-12f);
    float pos = 0.0f, neg = 0.0f;
    if (j < NN) {
        const float2 qv = *(const float2*)(ws + OFF_QN + j * 128 + 2 * lane);
        float dt = qv.x * kv.x + qv.y * kv.y;
        for (int o = 32; o; o >>= 1) dt += __shfl_xor(dt, o);
        float sim = fminf(fmaxf(fmaf(0.5f * invkn, dt, 0.5f), EPS), ONE_M_EPS);
        pos = -__logf(sim);
    } else {
#pragma unroll
        for (int n = 0; n < NN; n++) {
            const float2 qv = *(const float2*)(ws + OFF_QN + n * 128 + 2 * lane);
            float dt = qv.x * kv.x + qv.y * kv.y;
            for (int o = 32; o; o >>= 1) dt += __shfl_xor(dt, o);
            float om = fminf(fmaxf(fmaf(-0.5f * invkn, dt, 0.5f), EPS), ONE_M_EPS);
            neg -= __logf(om);
        }
    }
    __shared__ float sb[2][4];
    int w = threadIdx.x >> 6;
    if (!lane) { sb[0][w] = pos; sb[1][w] = neg; }
    __syncthreads();
    if (threadIdx.x == 0) {
        float ps = sb[0][0] + sb[0][1] + sb[0][2] + sb[0][3];
        float ng = sb[1][0] + sb[1][1] + sb[1][2] + sb[1][3];
        if (ps != 0.0f) atomicAdd(ws + OFF_ACCCL + 0, ps);
        if (ng != 0.0f) atomicAdd(ws + OFF_ACCCL + 1, ng);
    }
}

// ---------------- Final scalar combine ----------------
__global__ void finalize(float* __restrict__ out, const float* __restrict__ ws) {
    if (threadIdx.x != 0) return;
    float gp = 0, gn = 0, lsh = 0;
    for (int b = 0; b < 8; b++) {
        const float* a = ws + OFF_ACC + (size_t)b * 6;
        float pc = a[5];
        float nc = (float)((size_t)LL * SS) - pc;
        gp += a[0] / fmaxf(pc, 1.0f);
        gn += a[1] / fmaxf(nc, 1.0f);
        lsh += (a[2] + a[3]) * 0.5f + a[4] / fmaxf(nc, 1.0f);
    }
    gp *= 0.125f; gn *= 0.125f; lsh *= 0.125f;
    float lgeo = gp + gn;
    float lgw = (0.5f * lgeo + 0.5f * lsh) * 0.5f;
    float clp = ws[OFF_ACCCL + 0] / 8.0f;
    float cln = ws[OFF_ACCCL + 1] / (8.0f * 2040.0f);
    float lcl = (clp + cln) * 0.5f * 0.5f;
    out[OUT_SCAL + 0] = lgw + lcl;
    out[OUT_SCAL + 1] = gp;
    out[OUT_SCAL + 2] = gn;
    out[OUT_SCAL + 3] = lsh;
    out[OUT_SCAL + 4] = lcl;
}

extern "C" void kernel_launch(void* const* d_in, const int* in_sizes, int n_in,
                              void* d_out, int out_size, void* d_ws, size_t ws_size,
                              hipStream_t stream) {
    const float* q_geo   = (const float*)d_in[0];
    const float* q_cl    = (const float*)d_in[1];
    const float* geo_pos = (const float*)d_in[2];
    const float* cl_pos  = (const float*)d_in[3];
    const int*   label   = (const int*)d_in[4];
    const int*   idx     = (const int*)d_in[5];
    float* out = (float*)d_out;
    float* ws  = (float*)d_ws;
    float* dot = ws;

    prep<<<dim3(1), dim3(512), 0, stream>>>(q_cl, cl_pos, idx, out, ws);
    convert<<<dim3(4096), dim3(256), 0, stream>>>(q_geo, geo_pos, ws);
    gemm_dot<<<dim3(8, 8, 8), dim3(256), 0, stream>>>(ws, dot);
    stats<<<dim3(512), dim3(256), 0, stream>>>(dot, ws);
    ccomb<<<dim3(32), dim3(256), 0, stream>>>(ws);
    softmax16<<<dim3(16), dim3(256), 0, stream>>>(ws, out);
    main_loss<<<dim3(256, 8), dim3(256), 0, stream>>>(dot, label, out, ws);
    contrast<<<dim3(512), dim3(256), 0, stream>>>(cl_pos, idx, ws);
    finalize<<<dim3(1), dim3(64), 0, stream>>>(out, ws);
}